// Round 1
// baseline (6782.878 us; speedup 1.0000x reference)
//
#include <hip/hip_runtime.h>
#include <hip/hip_fp16.h>

#define NN 8192
#define DD 32
#define REGV 0.1f

typedef unsigned int uint;

static __device__ __forceinline__ uint pack2h(float a, float b) {
  __half2 h = __halves2half2(__float2half(a), __float2half(b));
  return __builtin_bit_cast(uint, h);
}

// ---------------- softmax over 8192 elements (one block per array) ----------------
__global__ __launch_bounds__(1024) void softmax_k(const float* __restrict__ A,
                                                  const float* __restrict__ B,
                                                  float* __restrict__ mu,
                                                  float* __restrict__ nu) {
  const float* in = (blockIdx.x == 0) ? A : B;
  float* out = (blockIdx.x == 0) ? mu : nu;
  int tid = threadIdx.x;
  float v[8];
  float m = -1e30f;
#pragma unroll
  for (int k = 0; k < 8; k++) { v[k] = in[tid + k * 1024]; m = fmaxf(m, v[k]); }
#pragma unroll
  for (int o = 1; o < 64; o <<= 1) m = fmaxf(m, __shfl_xor(m, o));
  __shared__ float red[16];
  __shared__ float bval;
  int wid = tid >> 6, lane = tid & 63;
  if (lane == 0) red[wid] = m;
  __syncthreads();
  if (tid == 0) { float t = red[0]; for (int k = 1; k < 16; k++) t = fmaxf(t, red[k]); bval = t; }
  __syncthreads();
  m = bval;
  float e[8]; float s = 0.f;
#pragma unroll
  for (int k = 0; k < 8; k++) { e[k] = __expf(v[k] - m); s += e[k]; }
#pragma unroll
  for (int o = 1; o < 64; o <<= 1) s += __shfl_xor(s, o);
  __syncthreads();            // everyone has read bval(max); red reads done
  if (lane == 0) red[wid] = s;
  __syncthreads();
  if (tid == 0) { float t = 0.f; for (int k = 0; k < 16; k++) t += red[k]; bval = t; }
  __syncthreads();
  float inv = 1.0f / bval;
#pragma unroll
  for (int k = 0; k < 8; k++) out[tid + k * 1024] = e[k] * inv;
}

// ---------------- build K (row-major) and KT (row-major transpose), fp16 ----------------
// tile: 32 rows (i) x 256 cols (j); one thread per column.
__global__ __launch_bounds__(256) void build_k(const float* __restrict__ X,
                                               const float* __restrict__ Y,
                                               __half* __restrict__ K,
                                               __half* __restrict__ KT, int hasKT) {
  __shared__ float lx[32][DD];
  __shared__ float lx2[32];
  __shared__ __half lk[32][256];
  int tid = threadIdx.x;
  int rb = (blockIdx.x >> 5) * 32;
  int cb = (blockIdx.x & 31) * 256;
  {
    int r = tid >> 3, dq = (tid & 7) * 4;
    float4 vv = *(const float4*)&X[(size_t)(rb + r) * DD + dq];
    lx[r][dq] = vv.x; lx[r][dq + 1] = vv.y; lx[r][dq + 2] = vv.z; lx[r][dq + 3] = vv.w;
  }
  __syncthreads();
  if (tid < 32) {
    float s = 0.f;
#pragma unroll
    for (int d = 0; d < DD; d++) s = fmaf(lx[tid][d], lx[tid][d], s);
    lx2[tid] = s;
  }
  int j = cb + tid;
  float yv[DD]; float y2 = 0.f;
#pragma unroll
  for (int dq = 0; dq < DD; dq += 4) {
    float4 vv = *(const float4*)&Y[(size_t)j * DD + dq];
    yv[dq] = vv.x; yv[dq + 1] = vv.y; yv[dq + 2] = vv.z; yv[dq + 3] = vv.w;
    y2 = fmaf(vv.x, vv.x, fmaf(vv.y, vv.y, fmaf(vv.z, vv.z, fmaf(vv.w, vv.w, y2))));
  }
  __syncthreads();
  float kv[32];
#pragma unroll
  for (int r = 0; r < 32; r++) {
    float dot = 0.f;
#pragma unroll
    for (int dq = 0; dq < DD; dq += 4) {
      float4 xx = *(const float4*)&lx[r][dq];
      dot = fmaf(xx.x, yv[dq], fmaf(xx.y, yv[dq + 1], fmaf(xx.z, yv[dq + 2], fmaf(xx.w, yv[dq + 3], dot))));
    }
    float d2 = lx2[r] + y2 - 2.0f * dot;
    float Mv = sqrtf(fmaxf(d2, 1e-12f));
    float kk = __expf(-Mv * (1.0f / REGV));
    kv[r] = kk;
    lk[r][tid] = __float2half(kk);
  }
  if (hasKT) {
    uint4* dst = (uint4*)&KT[(size_t)j * NN + rb];   // thread writes KT row-segment: 32 halves
#pragma unroll
    for (int qq = 0; qq < 4; qq++) {
      uint4 w;
      w.x = pack2h(kv[8 * qq + 0], kv[8 * qq + 1]);
      w.y = pack2h(kv[8 * qq + 2], kv[8 * qq + 3]);
      w.z = pack2h(kv[8 * qq + 4], kv[8 * qq + 5]);
      w.w = pack2h(kv[8 * qq + 6], kv[8 * qq + 7]);
      dst[qq] = w;
    }
  }
  __syncthreads();
  {
    // coalesced row-major K writes via LDS bounce
    int r = tid >> 3, seg = tid & 7;
    const float4* src = (const float4*)&lk[r][seg * 32];
    float4* dst = (float4*)&K[(size_t)(rb + r) * NN + cb + seg * 32];
#pragma unroll
    for (int q = 0; q < 4; q++) dst[q] = src[q];
  }
}

// ---------------- generic partialized matvec: out_part[rc][col] = sum_{rows in rc} mat[row][col]*u[row]
// u[row] = init_const (if >0) else w[row] / sum_r in_part[r][row]
// grid = 16 col-chunks x 32 row-chunks, 256 threads, 2 cols/thread (half2)
__global__ __launch_bounds__(256) void mv_k(const __half* __restrict__ mat,
                                            const float* __restrict__ in_part, int in_parts,
                                            const float* __restrict__ w,
                                            float* __restrict__ out_part, float init_const) {
  int tid = threadIdx.x;
  int cc = blockIdx.x & 15;
  int rc = blockIdx.x >> 4;
  __shared__ float lu[256];
  {
    int i = rc * 256 + tid;
    float u;
    if (init_const > 0.f) {
      u = init_const;
    } else {
      float t = 0.f;
      for (int r = 0; r < in_parts; r++) t += in_part[r * NN + i];
      u = w[i] / t;
    }
    lu[tid] = u;
  }
  __syncthreads();
  const __half2* M2 = (const __half2*)mat;
  int j2 = cc * 256 + tid;
  size_t base = (size_t)rc * 256 * 4096 + j2;
  float ax = 0.f, ay = 0.f;
#pragma unroll 4
  for (int ii = 0; ii < 256; ii += 4) {
    float4 u4 = *(const float4*)&lu[ii];
    __half2 h0 = M2[base + (size_t)(ii + 0) * 4096];
    __half2 h1 = M2[base + (size_t)(ii + 1) * 4096];
    __half2 h2v = M2[base + (size_t)(ii + 2) * 4096];
    __half2 h3 = M2[base + (size_t)(ii + 3) * 4096];
    float2 f0 = __half22float2(h0), f1 = __half22float2(h1);
    float2 f2 = __half22float2(h2v), f3 = __half22float2(h3);
    ax = fmaf(f0.x, u4.x, ax); ay = fmaf(f0.y, u4.x, ay);
    ax = fmaf(f1.x, u4.y, ax); ay = fmaf(f1.y, u4.y, ay);
    ax = fmaf(f2.x, u4.z, ax); ay = fmaf(f2.y, u4.z, ay);
    ax = fmaf(f3.x, u4.w, ax); ay = fmaf(f3.y, u4.w, ay);
  }
  ((float2*)out_part)[(size_t)rc * 4096 + j2] = make_float2(ax, ay);
}

// ---------------- fallback K·v on row-major K (only if ws can't hold KT) ----------------
// t_part has 16 partials in this mode.
__global__ __launch_bounds__(256) void kv_rows_k(const __half* __restrict__ K,
                                                 const float* __restrict__ s_part,
                                                 const float* __restrict__ nu,
                                                 float* __restrict__ t_part) {
  int tid = threadIdx.x;
  int cc = blockIdx.x & 15;   // 16 col chunks of 512
  int rc = blockIdx.x >> 4;   // 32 row chunks of 256
  __shared__ float lv[512];
#pragma unroll
  for (int q = 0; q < 2; q++) {
    int j = cc * 512 + q * 256 + tid;
    float s = 0.f;
    for (int r = 0; r < 32; r++) s += s_part[r * NN + j];
    lv[q * 256 + tid] = nu[j] / s;
  }
  __syncthreads();
  int wid = tid >> 6, lane = tid & 63;
  const __half2* K2 = (const __half2*)K;
  const float2* lv2 = (const float2*)lv;
  float2 vm0 = lv2[lane], vm1 = lv2[lane + 64], vm2 = lv2[lane + 128], vm3 = lv2[lane + 192];
  for (int k = 0; k < 64; k++) {
    int i = rc * 256 + wid + 4 * k;
    size_t rowb = (size_t)i * 4096 + cc * 256;
    __half2 h0 = K2[rowb + lane];
    __half2 h1 = K2[rowb + lane + 64];
    __half2 h2v = K2[rowb + lane + 128];
    __half2 h3 = K2[rowb + lane + 192];
    float2 f0 = __half22float2(h0), f1 = __half22float2(h1);
    float2 f2 = __half22float2(h2v), f3 = __half22float2(h3);
    float a = 0.f;
    a = fmaf(f0.x, vm0.x, a); a = fmaf(f0.y, vm0.y, a);
    a = fmaf(f1.x, vm1.x, a); a = fmaf(f1.y, vm1.y, a);
    a = fmaf(f2.x, vm2.x, a); a = fmaf(f2.y, vm2.y, a);
    a = fmaf(f3.x, vm3.x, a); a = fmaf(f3.y, vm3.y, a);
#pragma unroll
    for (int o = 1; o < 64; o <<= 1) a += __shfl_xor(a, o);
    if (lane == 0) t_part[cc * NN + i] = a;
  }
}

// ---------------- final loss: sum_ij u_i K_ij M_ij v_j (M recomputed from points) ----------------
// tile 128 rows x 256 cols; grid = 64 x 32 = 2048
__global__ __launch_bounds__(256) void loss_k(const float* __restrict__ X, const float* __restrict__ Y,
                                              const __half* __restrict__ Km,
                                              const float* __restrict__ t_part, int t_parts,
                                              const float* __restrict__ s_part,
                                              const float* __restrict__ mu, const float* __restrict__ nu,
                                              float* __restrict__ part) {
  int tid = threadIdx.x;
  int rb = (int)(blockIdx.x >> 5) * 128;
  int cb = (int)(blockIdx.x & 31) * 256;
  __shared__ float lx[128][DD];
  __shared__ float lx2[128];
  __shared__ float lu[128];
#pragma unroll
  for (int q = 0; q < 4; q++) {
    int idx = tid + q * 256;
    int r = idx >> 3, dq = (idx & 7) * 4;
    float4 vv = *(const float4*)&X[(size_t)(rb + r) * DD + dq];
    lx[r][dq] = vv.x; lx[r][dq + 1] = vv.y; lx[r][dq + 2] = vv.z; lx[r][dq + 3] = vv.w;
  }
  __syncthreads();
  if (tid < 128) {
    int i = rb + tid;
    float t = 0.f;
    for (int r = 0; r < t_parts; r++) t += t_part[r * NN + i];
    lu[tid] = mu[i] / t;
    float s2 = 0.f;
#pragma unroll
    for (int d = 0; d < DD; d++) s2 = fmaf(lx[tid][d], lx[tid][d], s2);
    lx2[tid] = s2;
  }
  int j = cb + tid;
  float yv[DD]; float y2 = 0.f;
#pragma unroll
  for (int dq = 0; dq < DD; dq += 4) {
    float4 vv = *(const float4*)&Y[(size_t)j * DD + dq];
    yv[dq] = vv.x; yv[dq + 1] = vv.y; yv[dq + 2] = vv.z; yv[dq + 3] = vv.w;
    y2 = fmaf(vv.x, vv.x, fmaf(vv.y, vv.y, fmaf(vv.z, vv.z, fmaf(vv.w, vv.w, y2))));
  }
  float sacc = 0.f;
  for (int r = 0; r < 32; r++) sacc += s_part[r * NN + j];
  float v = nu[j] / sacc;
  __syncthreads();
  float acc = 0.f;
  for (int r = 0; r < 128; r++) {
    float kf = __half2float(Km[(size_t)(rb + r) * NN + j]);
    float dot = 0.f;
#pragma unroll
    for (int dq = 0; dq < DD; dq += 4) {
      float4 xx = *(const float4*)&lx[r][dq];
      dot = fmaf(xx.x, yv[dq], fmaf(xx.y, yv[dq + 1], fmaf(xx.z, yv[dq + 2], fmaf(xx.w, yv[dq + 3], dot))));
    }
    float d2 = lx2[r] + y2 - 2.0f * dot;
    float Mv = sqrtf(fmaxf(d2, 1e-12f));
    acc = fmaf(lu[r] * kf * Mv, v, acc);
  }
#pragma unroll
  for (int o = 1; o < 64; o <<= 1) acc += __shfl_xor(acc, o);
  __shared__ float r4[4];
  if ((tid & 63) == 0) r4[tid >> 6] = acc;
  __syncthreads();
  if (tid == 0) part[blockIdx.x] = r4[0] + r4[1] + r4[2] + r4[3];
}

__global__ __launch_bounds__(256) void finish_k(const float* __restrict__ part, float* __restrict__ out) {
  int tid = threadIdx.x;
  float s = 0.f;
  for (int k = tid; k < 2048; k += 256) s += part[k];
#pragma unroll
  for (int o = 1; o < 64; o <<= 1) s += __shfl_xor(s, o);
  __shared__ float r4[4];
  if ((tid & 63) == 0) r4[tid >> 6] = s;
  __syncthreads();
  if (tid == 0) out[0] = r4[0] + r4[1] + r4[2] + r4[3];
}

extern "C" void kernel_launch(void* const* d_in, const int* in_sizes, int n_in,
                              void* d_out, int out_size, void* d_ws, size_t ws_size,
                              hipStream_t stream) {
  const float* X = (const float*)d_in[0];
  const float* Y = (const float*)d_in[1];
  const float* sd = (const float*)d_in[2];
  const float* td = (const float*)d_in[3];
  float* out = (float*)d_out;

  char* p = (char*)d_ws;
  const size_t need_full = 270606336ULL;  // K + KT + mu + nu + s_part + t_part + part
  bool full = ws_size >= need_full;

  __half* K = (__half*)p; p += (size_t)NN * NN * 2;
  __half* KT = nullptr;
  if (full) { KT = (__half*)p; p += (size_t)NN * NN * 2; }
  float* mu = (float*)p; p += (size_t)NN * 4;
  float* nu = (float*)p; p += (size_t)NN * 4;
  float* s_part = (float*)p; p += (size_t)32 * NN * 4;
  float* t_part = (float*)p; p += (size_t)32 * NN * 4;
  float* part = (float*)p;

  softmax_k<<<2, 1024, 0, stream>>>(sd, td, mu, nu);
  build_k<<<8192, 256, 0, stream>>>(X, Y, K, KT, full ? 1 : 0);

  int t_parts = full ? 32 : 16;
  for (int it = 0; it < 100; it++) {
    // s_part <- partials of K^T u   (u from t_part, or u0=1/N on first iter)
    mv_k<<<512, 256, 0, stream>>>(K, t_part, t_parts, mu, s_part, it == 0 ? (1.0f / NN) : 0.f);
    // t_part <- partials of K v     (v = nu / sum(s_part))
    if (full)
      mv_k<<<512, 256, 0, stream>>>(KT, s_part, 32, nu, t_part, 0.f);
    else
      kv_rows_k<<<512, 256, 0, stream>>>(K, s_part, nu, t_part);
  }

  loss_k<<<2048, 256, 0, stream>>>(X, Y, K, t_part, t_parts, s_part, mu, nu, part);
  finish_k<<<1, 256, 0, stream>>>(part, out);
}

// Round 2
// 3647.414 us; speedup vs baseline: 1.8596x; 1.8596x over previous
//
#include <hip/hip_runtime.h>

#define NN 8192
#define DD 32
#define REGV_INV 10.0f
#define KSCALE 512.0f
#define NPART 256

typedef unsigned int uint;
typedef unsigned char uchar;
typedef float vfloat2 __attribute__((ext_vector_type(2)));

static __device__ __forceinline__ uint pack4_fp8(float a, float b, float c, float d) {
  uint v = 0;
  v = __builtin_amdgcn_cvt_pk_fp8_f32(a, b, v, false);
  v = __builtin_amdgcn_cvt_pk_fp8_f32(c, d, v, true);
  return v;
}

static __device__ __forceinline__ void fma4_fp8(uint q, float ur, float* a) {
  vfloat2 lo = __builtin_amdgcn_cvt_pk_f32_fp8(q, false);
  vfloat2 hi = __builtin_amdgcn_cvt_pk_f32_fp8(q, true);
  a[0] = fmaf(lo.x, ur, a[0]);
  a[1] = fmaf(lo.y, ur, a[1]);
  a[2] = fmaf(hi.x, ur, a[2]);
  a[3] = fmaf(hi.y, ur, a[3]);
}

// ---------------- softmax over 8192 elements (one block per array) ----------------
__global__ __launch_bounds__(1024) void softmax_k(const float* __restrict__ A,
                                                  const float* __restrict__ B,
                                                  float* __restrict__ mu,
                                                  float* __restrict__ nu) {
  const float* in = (blockIdx.x == 0) ? A : B;
  float* out = (blockIdx.x == 0) ? mu : nu;
  int tid = threadIdx.x;
  float v[8];
  float m = -1e30f;
#pragma unroll
  for (int k = 0; k < 8; k++) { v[k] = in[tid + k * 1024]; m = fmaxf(m, v[k]); }
#pragma unroll
  for (int o = 1; o < 64; o <<= 1) m = fmaxf(m, __shfl_xor(m, o));
  __shared__ float red[16];
  __shared__ float bval;
  int wid = tid >> 6, lane = tid & 63;
  if (lane == 0) red[wid] = m;
  __syncthreads();
  if (tid == 0) { float t = red[0]; for (int k = 1; k < 16; k++) t = fmaxf(t, red[k]); bval = t; }
  __syncthreads();
  m = bval;
  float e[8]; float s = 0.f;
#pragma unroll
  for (int k = 0; k < 8; k++) { e[k] = __expf(v[k] - m); s += e[k]; }
#pragma unroll
  for (int o = 1; o < 64; o <<= 1) s += __shfl_xor(s, o);
  __syncthreads();
  if (lane == 0) red[wid] = s;
  __syncthreads();
  if (tid == 0) { float t = 0.f; for (int k = 0; k < 16; k++) t += red[k]; bval = t; }
  __syncthreads();
  float inv = 1.0f / bval;
#pragma unroll
  for (int k = 0; k < 8; k++) out[tid + k * 1024] = e[k] * inv;
}

// ---------------- build K (row-major) and KT (transpose), fp8 e4m3 scaled by KSCALE ----------------
// tile: 32 rows (i) x 256 cols (j); one thread per column.
__global__ __launch_bounds__(256) void build8_k(const float* __restrict__ X,
                                                const float* __restrict__ Y,
                                                uchar* __restrict__ K,
                                                uchar* __restrict__ KT) {
  __shared__ float lx[32][DD];
  __shared__ float lx2[32];
  __shared__ __align__(16) uchar lkb[32][256];
  int tid = threadIdx.x;
  int rb = (blockIdx.x >> 5) * 32;
  int cb = (blockIdx.x & 31) * 256;
  {
    int r = tid >> 3, dq = (tid & 7) * 4;
    float4 vv = *(const float4*)&X[(size_t)(rb + r) * DD + dq];
    lx[r][dq] = vv.x; lx[r][dq + 1] = vv.y; lx[r][dq + 2] = vv.z; lx[r][dq + 3] = vv.w;
  }
  __syncthreads();
  if (tid < 32) {
    float s = 0.f;
#pragma unroll
    for (int d = 0; d < DD; d++) s = fmaf(lx[tid][d], lx[tid][d], s);
    lx2[tid] = s;
  }
  int j = cb + tid;
  float yv[DD]; float y2 = 0.f;
#pragma unroll
  for (int dq = 0; dq < DD; dq += 4) {
    float4 vv = *(const float4*)&Y[(size_t)j * DD + dq];
    yv[dq] = vv.x; yv[dq + 1] = vv.y; yv[dq + 2] = vv.z; yv[dq + 3] = vv.w;
    y2 = fmaf(vv.x, vv.x, fmaf(vv.y, vv.y, fmaf(vv.z, vv.z, fmaf(vv.w, vv.w, y2))));
  }
  __syncthreads();
  float kv[32];
#pragma unroll
  for (int r = 0; r < 32; r++) {
    float dot = 0.f;
#pragma unroll
    for (int dq = 0; dq < DD; dq += 4) {
      float4 xx = *(const float4*)&lx[r][dq];
      dot = fmaf(xx.x, yv[dq], fmaf(xx.y, yv[dq + 1], fmaf(xx.z, yv[dq + 2], fmaf(xx.w, yv[dq + 3], dot))));
    }
    float d2 = lx2[r] + y2 - 2.0f * dot;
    float Mv = sqrtf(fmaxf(d2, 1e-12f));
    float kk = fminf(__expf(-Mv * REGV_INV) * KSCALE, 448.f);
    kv[r] = kk;
    lkb[r][tid] = (uchar)(pack4_fp8(kk, 0.f, 0.f, 0.f) & 0xffu);
  }
  {
    // KT: thread owns column j -> contiguous 32 bytes of KT row j
    uint w0 = pack4_fp8(kv[0], kv[1], kv[2], kv[3]);
    uint w1 = pack4_fp8(kv[4], kv[5], kv[6], kv[7]);
    uint w2 = pack4_fp8(kv[8], kv[9], kv[10], kv[11]);
    uint w3 = pack4_fp8(kv[12], kv[13], kv[14], kv[15]);
    uint w4 = pack4_fp8(kv[16], kv[17], kv[18], kv[19]);
    uint w5 = pack4_fp8(kv[20], kv[21], kv[22], kv[23]);
    uint w6 = pack4_fp8(kv[24], kv[25], kv[26], kv[27]);
    uint w7 = pack4_fp8(kv[28], kv[29], kv[30], kv[31]);
    uint4* dst = (uint4*)&KT[(size_t)j * NN + rb];
    dst[0] = make_uint4(w0, w1, w2, w3);
    dst[1] = make_uint4(w4, w5, w6, w7);
  }
  __syncthreads();
  {
    // coalesced row-major K writes via LDS bounce
    int r = tid >> 3, seg = tid & 7;
    const uint4* src = (const uint4*)&lkb[r][seg * 32];
    uint4* dstk = (uint4*)&K[(size_t)(rb + r) * NN + cb + seg * 32];
    dstk[0] = src[0];
    dstk[1] = src[1];
  }
}

// ---------------- fp8 partialized matvec: out_part[rc][col] = sum_{rows in rc} mat[row][col]*u[row]
// u[row] = init_const (if >0) else w[row] / sum_r in_part[r][row]
// grid = 2 col-chunks (4096 cols) x 256 row-chunks (32 rows); 16 cols/thread via uint4 (16B/lane)
__global__ __launch_bounds__(256) void mv8_k(const uint4* __restrict__ mat16,
                                             const float* __restrict__ in_part,
                                             const float* __restrict__ w,
                                             float* __restrict__ out_part,
                                             float init_const) {
  int tid = threadIdx.x;
  int cc = blockIdx.x & 1;
  int rc = blockIdx.x >> 1;
  __shared__ float lu[32];
  __shared__ float lup[8][32];
  int rr = tid & 31, g = tid >> 5;
  if (init_const > 0.f) {
    if (tid < 32) lu[tid] = init_const;
  } else {
    int i = rc * 32 + rr;
    float t = 0.f;
#pragma unroll 8
    for (int r = g * 32; r < (g + 1) * 32; r++) t += in_part[(size_t)r * NN + i];
    lup[g][rr] = t;
  }
  __syncthreads();
  if (init_const <= 0.f && tid < 32) {
    float s = 0.f;
#pragma unroll
    for (int g2 = 0; g2 < 8; g2++) s += lup[g2][tid];
    lu[tid] = w[rc * 32 + tid] / s;
  }
  __syncthreads();
  int j4 = cc * 256 + tid;                     // uint4 index within row (512 per row)
  size_t base = (size_t)(rc * 32) * 512 + j4;
  float a[16];
#pragma unroll
  for (int k = 0; k < 16; k++) a[k] = 0.f;
#pragma unroll 4
  for (int r = 0; r < 32; r++) {
    float ur = lu[r];
    uint4 q = mat16[base + (size_t)r * 512];
    fma4_fp8(q.x, ur, a + 0);
    fma4_fp8(q.y, ur, a + 4);
    fma4_fp8(q.z, ur, a + 8);
    fma4_fp8(q.w, ur, a + 12);
  }
  float4* op = (float4*)out_part;
  size_t ob = (size_t)rc * 2048 + cc * 1024 + tid * 4;
#pragma unroll
  for (int qq = 0; qq < 4; qq++)
    op[ob + qq] = make_float4(a[4 * qq], a[4 * qq + 1], a[4 * qq + 2], a[4 * qq + 3]);
}

// ---------------- materialize u = mu/sum(t_part), v = nu/sum(s_part) ----------------
__global__ __launch_bounds__(256) void reduce_uv_k(const float* __restrict__ t_part,
                                                   const float* __restrict__ s_part,
                                                   const float* __restrict__ mu,
                                                   const float* __restrict__ nu,
                                                   float* __restrict__ uarr,
                                                   float* __restrict__ varr) {
  int tid = threadIdx.x;
  int b = blockIdx.x;
  int i = (b & 31) * 256 + tid;
  if (b < 32) {
    float t = 0.f;
#pragma unroll 8
    for (int r = 0; r < NPART; r++) t += t_part[(size_t)r * NN + i];
    uarr[i] = mu[i] / t;
  } else {
    float t = 0.f;
#pragma unroll 8
    for (int r = 0; r < NPART; r++) t += s_part[(size_t)r * NN + i];
    varr[i] = nu[i] / t;
  }
}

// ---------------- final loss: sum_ij u_i K'_ij M_ij v_j, K' recomputed (exp + fp8 round-trip) ----------------
// tile 128 rows x 512 cols, 2 cols/thread; grid = 64 x 16 = 1024
__global__ __launch_bounds__(256) void loss_k(const float* __restrict__ X, const float* __restrict__ Y,
                                              const float* __restrict__ uarr, const float* __restrict__ varr,
                                              float* __restrict__ part) {
  int tid = threadIdx.x;
  int rb = (int)(blockIdx.x >> 4) * 128;
  int cb = (int)(blockIdx.x & 15) * 512;
  __shared__ float lx[128][DD];
  __shared__ float lx2[128];
  __shared__ float lu[128];
#pragma unroll
  for (int q = 0; q < 4; q++) {
    int idx = tid + q * 256;
    int r = idx >> 3, dq = (idx & 7) * 4;
    float4 vv = *(const float4*)&X[(size_t)(rb + r) * DD + dq];
    lx[r][dq] = vv.x; lx[r][dq + 1] = vv.y; lx[r][dq + 2] = vv.z; lx[r][dq + 3] = vv.w;
  }
  __syncthreads();
  if (tid < 128) {
    float s = 0.f;
#pragma unroll
    for (int d = 0; d < DD; d++) s = fmaf(lx[tid][d], lx[tid][d], s);
    lx2[tid] = s;
    lu[tid] = uarr[rb + tid];
  }
  int j0 = cb + tid * 2;
  float yv0[DD], yv1[DD]; float y20 = 0.f, y21 = 0.f;
#pragma unroll
  for (int dq = 0; dq < DD; dq += 4) {
    float4 a = *(const float4*)&Y[(size_t)j0 * DD + dq];
    float4 b = *(const float4*)&Y[(size_t)(j0 + 1) * DD + dq];
    yv0[dq] = a.x; yv0[dq + 1] = a.y; yv0[dq + 2] = a.z; yv0[dq + 3] = a.w;
    y20 = fmaf(a.x, a.x, fmaf(a.y, a.y, fmaf(a.z, a.z, fmaf(a.w, a.w, y20))));
    yv1[dq] = b.x; yv1[dq + 1] = b.y; yv1[dq + 2] = b.z; yv1[dq + 3] = b.w;
    y21 = fmaf(b.x, b.x, fmaf(b.y, b.y, fmaf(b.z, b.z, fmaf(b.w, b.w, y21))));
  }
  float v0 = varr[j0], v1 = varr[j0 + 1];
  __syncthreads();
  float acc = 0.f;
  for (int r = 0; r < 128; r++) {
    float dot0 = 0.f, dot1 = 0.f;
#pragma unroll
    for (int dq = 0; dq < DD; dq += 4) {
      float4 xx = *(const float4*)&lx[r][dq];
      dot0 = fmaf(xx.x, yv0[dq], fmaf(xx.y, yv0[dq + 1], fmaf(xx.z, yv0[dq + 2], fmaf(xx.w, yv0[dq + 3], dot0))));
      dot1 = fmaf(xx.x, yv1[dq], fmaf(xx.y, yv1[dq + 1], fmaf(xx.z, yv1[dq + 2], fmaf(xx.w, yv1[dq + 3], dot1))));
    }
    float d20 = lx2[r] + y20 - 2.0f * dot0;
    float d21 = lx2[r] + y21 - 2.0f * dot1;
    float M0 = sqrtf(fmaxf(d20, 1e-12f));
    float M1 = sqrtf(fmaxf(d21, 1e-12f));
    float k0 = fminf(__expf(-M0 * REGV_INV) * KSCALE, 448.f);
    float k1 = fminf(__expf(-M1 * REGV_INV) * KSCALE, 448.f);
    // round-trip through fp8 so the loss uses EXACTLY the iteration matrix
    uint e = pack4_fp8(k0, k1, 0.f, 0.f);
    vfloat2 kk = __builtin_amdgcn_cvt_pk_f32_fp8(e, false);
    acc = fmaf(lu[r], kk.x * M0 * v0 + kk.y * M1 * v1, acc);
  }
#pragma unroll
  for (int o = 1; o < 64; o <<= 1) acc += __shfl_xor(acc, o);
  __shared__ float r4[4];
  if ((tid & 63) == 0) r4[tid >> 6] = acc;
  __syncthreads();
  if (tid == 0) part[blockIdx.x] = r4[0] + r4[1] + r4[2] + r4[3];
}

__global__ __launch_bounds__(256) void finish_k(const float* __restrict__ part, float* __restrict__ out) {
  int tid = threadIdx.x;
  float s = 0.f;
  for (int k = tid; k < 1024; k += 256) s += part[k];
#pragma unroll
  for (int o = 1; o < 64; o <<= 1) s += __shfl_xor(s, o);
  __shared__ float r4[4];
  if ((tid & 63) == 0) r4[tid >> 6] = s;
  __syncthreads();
  if (tid == 0) out[0] = r4[0] + r4[1] + r4[2] + r4[3];
}

extern "C" void kernel_launch(void* const* d_in, const int* in_sizes, int n_in,
                              void* d_out, int out_size, void* d_ws, size_t ws_size,
                              hipStream_t stream) {
  const float* X = (const float*)d_in[0];
  const float* Y = (const float*)d_in[1];
  const float* sd = (const float*)d_in[2];
  const float* td = (const float*)d_in[3];
  float* out = (float*)d_out;

  char* p = (char*)d_ws;
  uchar* K = (uchar*)p; p += (size_t)NN * NN;          // 67.1 MB
  uchar* KT = (uchar*)p; p += (size_t)NN * NN;         // 67.1 MB
  float* mu = (float*)p; p += (size_t)NN * 4;
  float* nu = (float*)p; p += (size_t)NN * 4;
  float* uarr = (float*)p; p += (size_t)NN * 4;
  float* varr = (float*)p; p += (size_t)NN * 4;
  float* s_part = (float*)p; p += (size_t)NPART * NN * 4;   // 8 MB
  float* t_part = (float*)p; p += (size_t)NPART * NN * 4;   // 8 MB
  float* part = (float*)p;                                   // 4 KB

  softmax_k<<<2, 1024, 0, stream>>>(sd, td, mu, nu);
  build8_k<<<8192, 256, 0, stream>>>(X, Y, K, KT);

  for (int it = 0; it < 100; it++) {
    // s_part <- partials of K^T u   (u from t_part, or u0 = 1/N on first iter)
    mv8_k<<<512, 256, 0, stream>>>((const uint4*)K, t_part, mu, s_part, it == 0 ? (1.0f / NN) : 0.f);
    // t_part <- partials of K v     (v = nu / sum(s_part))
    mv8_k<<<512, 256, 0, stream>>>((const uint4*)KT, s_part, nu, t_part, 0.f);
  }

  reduce_uv_k<<<64, 256, 0, stream>>>(t_part, s_part, mu, nu, uarr, varr);
  loss_k<<<1024, 256, 0, stream>>>(X, Y, uarr, varr, part);
  finish_k<<<1, 256, 0, stream>>>(part, out);
}